// Round 7
// baseline (432.641 us; speedup 1.0000x reference)
//
#include <hip/hip_runtime.h>

#define B_ 8
#define T_ 2048
#define D_ 768
#define H_ 12
#define HS_ 64
#define LN_EPS 1e-5f
#define NC 32   // chunks
#define TC 64   // timesteps per chunk

typedef __attribute__((ext_vector_type(8))) short bf16x8;
typedef __attribute__((ext_vector_type(4))) float f32x4;

__device__ __forceinline__ ushort f2bf(float f) {
  unsigned u = __builtin_bit_cast(unsigned, f);
  unsigned r = (u + 0x7FFFu + ((u >> 16) & 1u)) >> 16;
  return (ushort)r;
}
__device__ __forceinline__ float bf2f(ushort u) {
  return __builtin_bit_cast(float, ((unsigned)u) << 16);
}

// fragment address: element (row tORs, col i) of a 64x64 tile in MFMA A/B-frag
// layout (m/n = tORs, k = i). 8 frags x 512 halves.
__device__ __forceinline__ int fragaddr(int t, int i) {
  return ((t >> 4) * 2 + (i >> 5)) * 512 + ((((i >> 3) & 3) * 16) + (t & 15)) * 8 + (i & 7);
}
// XOR swizzle (writer side, per element): spreads per-step lane stores across banks
__device__ __forceinline__ int fragswz(int i) {
  return (((i >> 3) & 3) << 3) ^ (((i >> 5) & 1) << 5);
}

// ---------------- canary ----------------
__global__ __launch_bounds__(256) void zero_out_kernel(float* __restrict__ out, int n) {
  for (int i = blockIdx.x * 256 + threadIdx.x; i < n; i += gridDim.x * 256)
    out[i] = 0.f;
}

// ---------------- weight cast ----------------
__global__ __launch_bounds__(256) void cast_w_kernel(
    const float* __restrict__ src, ushort* __restrict__ dst) {
  int idx = (blockIdx.x * 256 + threadIdx.x) * 4;
  float4 v = *reinterpret_cast<const float4*>(src + idx);
  ushort4 o;
  o.x = f2bf(v.x); o.y = f2bf(v.y); o.z = f2bf(v.z); o.w = f2bf(v.w);
  *reinterpret_cast<ushort4*>(dst + idx) = o;
}

// ---------------- LayerNorm ----------------
__global__ __launch_bounds__(256) void ln_kernel(
    const float* __restrict__ x, const float* __restrict__ gamma,
    const float* __restrict__ beta, ushort* __restrict__ xn) {
  const int wv = threadIdx.x >> 6;
  const int lane = threadIdx.x & 63;
  const int row = blockIdx.x * 4 + wv;
  const float* xr = x + (size_t)row * D_;
  float4 a[3];
#pragma unroll
  for (int s = 0; s < 3; ++s)
    a[s] = *reinterpret_cast<const float4*>(xr + s * 256 + lane * 4);
  float sum = 0.f;
#pragma unroll
  for (int s = 0; s < 3; ++s) sum += a[s].x + a[s].y + a[s].z + a[s].w;
#pragma unroll
  for (int off = 32; off; off >>= 1) sum += __shfl_xor(sum, off);
  float mu = sum * (1.f / 768.f);
  float vs = 0.f;
#pragma unroll
  for (int s = 0; s < 3; ++s) {
    float dx = a[s].x - mu, dy = a[s].y - mu, dz = a[s].z - mu, dw = a[s].w - mu;
    vs += dx * dx + dy * dy + dz * dz + dw * dw;
  }
#pragma unroll
  for (int off = 32; off; off >>= 1) vs += __shfl_xor(vs, off);
  float rs = rsqrtf(vs * (1.f / 768.f) + LN_EPS);
  ushort* orow = xn + (size_t)row * D_;
#pragma unroll
  for (int s = 0; s < 3; ++s) {
    int col = s * 256 + lane * 4;
    float4 g = *reinterpret_cast<const float4*>(gamma + col);
    float4 bb = *reinterpret_cast<const float4*>(beta + col);
    ushort4 o;
    o.x = f2bf((a[s].x - mu) * rs * g.x + bb.x);
    o.y = f2bf((a[s].y - mu) * rs * g.y + bb.y);
    o.z = f2bf((a[s].z - mu) * rs * g.z + bb.z);
    o.w = f2bf((a[s].w - mu) * rs * g.w + bb.w);
    *reinterpret_cast<ushort4*>(orow + col) = o;
  }
}

// ---------------- 256x256 8-phase bf16 MFMA GEMM, fragment-hoisted pipeline ----
// C[m,n] = sum_k A[m,k]*W[n,k].  K=768. 512 threads = 8 waves (2M x 4N).
// modes: 0 fp32 plain, 3 fp32 decay=1-sigmoid(val+bias),
//        5 cat -> k(d0 nat) / v(d1 FRAG layout) / r(d2 sigmoid nat) / xp(d3 nat)
__global__ __launch_bounds__(512, 2) void gemm256(
    const ushort* __restrict__ A, const ushort* __restrict__ W,
    float* __restrict__ Cf,
    ushort* __restrict__ d0, ushort* __restrict__ d1,
    ushort* __restrict__ d2, ushort* __restrict__ d3,
    const float* __restrict__ bias, int mode) {
  __shared__ __align__(16) ushort lds[65536];  // 128 KiB
  const int tid = threadIdx.x;
  const int wid = tid >> 6;
  const int lane = tid & 63;
  const int wr = wid >> 2, wc = wid & 3;
  const int fr = lane & 15, fq = lane >> 4;
  const int m0 = blockIdx.x * 256, n0 = blockIdx.y * 256;
  const int strow = tid >> 3;
  const int stblk = tid & 7;

  const int RA0 = wr * 8192;
  const int RA1 = 32768 + wr * 8192;
  const int RB0 = 16384 + (wc >> 1) * 8192 + (wc & 1) * 4096;
  const int RB1 = 49152 + (wc >> 1) * 8192 + (wc & 1) * 4096;

  f32x4 acc[8][4];
#pragma unroll
  for (int m = 0; m < 8; ++m)
#pragma unroll
    for (int n = 0; n < 4; ++n) acc[m][n] = (f32x4){0.f, 0.f, 0.f, 0.f};

#define STAGE_HALF(gb, grow0, kk0, roff)                                          \
  {                                                                               \
    _Pragma("unroll") for (int j = 0; j < 2; ++j) {                               \
      const int lr_ = j * 64 + strow;                                             \
      const int bs_ = stblk ^ (lr_ & 7);                                          \
      const ushort* s_ = (gb) + (size_t)((grow0) + lr_) * 768 + (kk0) + bs_ * 8;  \
      __builtin_amdgcn_global_load_lds(                                           \
          (const __attribute__((address_space(1))) void*)s_,                      \
          (__attribute__((address_space(3))) void*)(lds + (roff) + j * 4096 + wid * 512), \
          16, 0, 0);                                                              \
    }                                                                             \
  }

#define LDF(dst, base, rf, kk)                                                    \
  dst = *reinterpret_cast<const bf16x8*>(                                         \
      lds + (base) + ((rf)*16 + fr) * 64 + ((((kk)*4 + fq) ^ (fr & 7)) * 8));

#define MFMA_Q(mb, nb, aa, bb)                                                    \
  __builtin_amdgcn_s_setprio(1);                                                  \
  _Pragma("unroll") for (int m_ = 0; m_ < 4; ++m_)                                \
  _Pragma("unroll") for (int n_ = 0; n_ < 2; ++n_)                                \
  _Pragma("unroll") for (int k_ = 0; k_ < 2; ++k_)                                \
    acc[(mb) + m_][(nb) + n_] = __builtin_amdgcn_mfma_f32_16x16x32_bf16(          \
        aa[m_][k_], bb[n_][k_], acc[(mb) + m_][(nb) + n_], 0, 0, 0);              \
  __builtin_amdgcn_s_setprio(0);

#define LDF_AL(RA) \
  _Pragma("unroll") for (int m = 0; m < 4; ++m) { LDF(aL[m][0], RA, m, 0); LDF(aL[m][1], RA, m, 1); }
#define LDF_AH(RA) \
  _Pragma("unroll") for (int m = 0; m < 4; ++m) { LDF(aH[m][0], RA, m + 4, 0); LDF(aH[m][1], RA, m + 4, 1); }
#define LDF_BL(RB) \
  _Pragma("unroll") for (int n = 0; n < 2; ++n) { LDF(bL[n][0], RB, n, 0); LDF(bL[n][1], RB, n, 1); }
#define LDF_BH(RB) \
  _Pragma("unroll") for (int n = 0; n < 2; ++n) { LDF(bH[n][0], RB, n + 2, 0); LDF(bH[n][1], RB, n + 2, 1); }

  // ---- prologue: A0, B0 -> buf0; B1 -> buf1 ----
  STAGE_HALF(A, m0, 0, 0);
  STAGE_HALF(A, m0 + 128, 0, 8192);
  STAGE_HALF(W, n0, 0, 16384);
  STAGE_HALF(W, n0 + 128, 0, 24576);
  STAGE_HALF(W, n0, 64, 49152);
  STAGE_HALF(W, n0 + 128, 64, 57344);
  asm volatile("s_waitcnt vmcnt(4)" ::: "memory");
  __builtin_amdgcn_s_barrier();

  bf16x8 aL[4][2], aH[4][2], bL[2][2], bH[2][2];
  LDF_AL(RA0);
  LDF_BL(RB0);

  for (int i = 0; i < 6; ++i) {
    const int kQ = (2 * i + 1) * 64;
    const int kP2 = (2 * i + 2 <= 11 ? 2 * i + 2 : 11) * 64;
    const int kQ2 = (2 * i + 3 <= 11 ? 2 * i + 3 : 11) * 64;

    // ======== tile P = 2i (buf0) ========
    STAGE_HALF(A, m0, kQ, 32768);
    LDF_BH(RB0);
    __builtin_amdgcn_s_barrier();
    MFMA_Q(0, 0, aL, bL);
    __builtin_amdgcn_s_barrier();

    STAGE_HALF(A, m0 + 128, kQ, 40960);
    LDF_AH(RA0);
    __builtin_amdgcn_s_barrier();
    MFMA_Q(0, 2, aL, bH);
    __builtin_amdgcn_s_barrier();

    STAGE_HALF(W, n0, kP2, 16384);
    __builtin_amdgcn_s_barrier();
    MFMA_Q(4, 0, aH, bL);
    __builtin_amdgcn_s_barrier();

    STAGE_HALF(W, n0 + 128, kP2, 24576);
    asm volatile("s_waitcnt vmcnt(4)" ::: "memory");
    __builtin_amdgcn_s_barrier();
    LDF_AL(RA1);
    LDF_BL(RB1);
    MFMA_Q(4, 2, aH, bH);
    __builtin_amdgcn_s_barrier();

    // ======== tile Q = 2i+1 (buf1) ========
    STAGE_HALF(A, m0, kP2, 0);
    LDF_BH(RB1);
    __builtin_amdgcn_s_barrier();
    MFMA_Q(0, 0, aL, bL);
    __builtin_amdgcn_s_barrier();

    STAGE_HALF(A, m0 + 128, kP2, 8192);
    LDF_AH(RA1);
    __builtin_amdgcn_s_barrier();
    MFMA_Q(0, 2, aL, bH);
    __builtin_amdgcn_s_barrier();

    STAGE_HALF(W, n0, kQ2, 49152);
    __builtin_amdgcn_s_barrier();
    MFMA_Q(4, 0, aH, bL);
    __builtin_amdgcn_s_barrier();

    STAGE_HALF(W, n0 + 128, kQ2, 57344);
    asm volatile("s_waitcnt vmcnt(4)" ::: "memory");
    __builtin_amdgcn_s_barrier();
    LDF_AL(RA0);
    LDF_BL(RB0);
    MFMA_Q(4, 2, aH, bH);
    __builtin_amdgcn_s_barrier();
  }

  // ---- epilogue ----
  const int r0 = fq * 4;
  if (mode == 5) {
    const int sel = n0 >= 2304 ? 3 : n0 >= 1536 ? 2 : n0 >= 768 ? 1 : 0;
    const int nb = n0 - sel * 768;
    if (sel == 1) {
      // v -> fragment layout per (b,h,chunk) tile
#pragma unroll
      for (int mf = 0; mf < 8; ++mf)
#pragma unroll
        for (int nf = 0; nf < 4; ++nf) {
          int gr = m0 + wr * 128 + mf * 16 + r0;     // global M row (rr=0)
          int gc = nb + wc * 64 + nf * 16 + fr;      // 0..767
          int b = gr >> 11, t = gr & 2047;
          int c = t >> 6, s0 = t & 63;
          int h = gc >> 6, j = gc & 63;
          size_t addr = ((size_t)((b * 12 + h) * 32 + c)) * 4096 +
                        (size_t)(((j >> 4) * 2 + (s0 >> 5)) * 512 +
                                 (((s0 >> 3) & 3) * 16 + (j & 15)) * 8 + (s0 & 7));
          ushort4 o;
          o.x = f2bf(acc[mf][nf][0]); o.y = f2bf(acc[mf][nf][1]);
          o.z = f2bf(acc[mf][nf][2]); o.w = f2bf(acc[mf][nf][3]);
          *reinterpret_cast<ushort4*>(d1 + addr) = o;
        }
    } else {
      ushort* dst = sel == 0 ? d0 : sel == 2 ? d2 : d3;
      const bool sig = (sel == 2);
#pragma unroll
      for (int mf = 0; mf < 8; ++mf)
#pragma unroll
        for (int nf = 0; nf < 4; ++nf) {
          int gr = m0 + wr * 128 + mf * 16 + r0;
          int gc = nb + wc * 64 + nf * 16 + fr;
#pragma unroll
          for (int rr = 0; rr < 4; ++rr) {
            float v = acc[mf][nf][rr];
            if (sig) v = 1.f / (1.f + __expf(-v));
            dst[(size_t)(gr + rr) * 768 + gc] = f2bf(v);
          }
        }
    }
  } else if (mode == 3) {
#pragma unroll
    for (int mf = 0; mf < 8; ++mf)
#pragma unroll
      for (int nf = 0; nf < 4; ++nf) {
        int gr = m0 + wr * 128 + mf * 16 + r0;
        int gc = n0 + wc * 64 + nf * 16 + fr;
        float bv = bias[gc];
#pragma unroll
        for (int rr = 0; rr < 4; ++rr) {
          float u = acc[mf][nf][rr] + bv;
          Cf[(size_t)(gr + rr) * 768 + gc] = 1.f / (1.f + __expf(u));
        }
      }
  } else {
#pragma unroll
    for (int mf = 0; mf < 8; ++mf)
#pragma unroll
      for (int nf = 0; nf < 4; ++nf) {
        int gr = m0 + wr * 128 + mf * 16 + r0;
        int gc = n0 + wc * 64 + nf * 16 + fr;
#pragma unroll
        for (int rr = 0; rr < 4; ++rr)
          Cf[(size_t)(gr + rr) * 768 + gc] = acc[mf][nf][rr];
      }
  }
#undef STAGE_HALF
#undef LDF
#undef MFMA_Q
#undef LDF_AL
#undef LDF_AH
#undef LDF_BL
#undef LDF_BH
}

// ---------------- scan mc2: per (bh,c): walk cumprod + McT = kIA^T V ----------
// McT bf16 [j][i] per chunk; aend fp32.
__global__ __launch_bounds__(256) void scan_mc2(
    const ushort* __restrict__ kb, const float* __restrict__ df,
    const ushort* __restrict__ vbF, ushort* __restrict__ McT,
    float* __restrict__ aend) {
  __shared__ float dt[64 * 68];
  __shared__ ushort kt[64 * 72];
  __shared__ ushort kIAf[4096];
  __shared__ float part[256];
  const int bh = blockIdx.x, c = blockIdx.y;
  const int b = bh / H_, h = bh % H_;
  const int tid = threadIdx.x;
  const int w = tid >> 6, lane = tid & 63;
  {
    const int row = tid >> 2, c16 = (tid & 3) * 16;
    const ushort* gk = kb + ((size_t)(b * T_ + c * TC + row)) * D_ + h * HS_ + c16;
    const float* gd = df + ((size_t)(b * T_ + c * TC + row)) * D_ + h * HS_ + c16;
    uint4 k0 = *(const uint4*)gk;
    uint4 k1 = *(const uint4*)(gk + 8);
    *(uint4*)&kt[row * 72 + c16] = k0;
    *(uint4*)&kt[row * 72 + c16 + 8] = k1;
#pragma unroll
    for (int q = 0; q < 4; ++q)
      *(float4*)&dt[row * 68 + c16 + q * 4] = *(const float4*)(gd + q * 4);
  }
  __syncthreads();
  // split-scan cumprod: wave w owns t in [16w, 16w+16)
  float p = 1.f;
#pragma unroll
  for (int tt = 0; tt < 16; ++tt) p *= dt[(w * 16 + tt) * 68 + lane];
  part[w * 64 + lane] = p;
  __syncthreads();
  float a = 1.f;
  for (int w2 = 0; w2 < w; ++w2) a *= part[w2 * 64 + lane];
#pragma unroll
  for (int tt = 0; tt < 16; ++tt) {
    int t = w * 16 + tt;
    float d = dt[t * 68 + lane];
    float k = bf2f(kt[t * 72 + lane]);
    a *= d;
    kIAf[fragaddr(lane, t)] = f2bf(k / a);  // A-frag (m=i, k=s)
  }
  if (w == 3) aend[((size_t)bh * NC + c) * 64 + lane] = a;
  __syncthreads();

  const int fr = lane & 15, fq = lane >> 4;
  f32x4 acc[4];
#pragma unroll
  for (int nf = 0; nf < 4; ++nf) acc[nf] = (f32x4){0.f, 0.f, 0.f, 0.f};
  bf16x8 af[2];
  af[0] = *reinterpret_cast<const bf16x8*>(&kIAf[(w * 2 + 0) * 512 + lane * 8]);
  af[1] = *reinterpret_cast<const bf16x8*>(&kIAf[(w * 2 + 1) * 512 + lane * 8]);
  const ushort* vch = vbF + ((size_t)bh * NC + c) * 4096;
#pragma unroll
  for (int kk = 0; kk < 2; ++kk)
#pragma unroll
    for (int nf = 0; nf < 4; ++nf) {
      bf16x8 b8 = *reinterpret_cast<const bf16x8*>(vch + (nf * 2 + kk) * 512 + lane * 8);
      acc[nf] = __builtin_amdgcn_mfma_f32_16x16x32_bf16(af[kk], b8, acc[nf], 0, 0, 0);
    }
  ushort* mch = McT + ((size_t)bh * NC + c) * 4096;
#pragma unroll
  for (int nf = 0; nf < 4; ++nf) {
    ushort4 o;
    o.x = f2bf(acc[nf][0]); o.y = f2bf(acc[nf][1]);
    o.z = f2bf(acc[nf][2]); o.w = f2bf(acc[nf][3]);
    *reinterpret_cast<ushort4*>(&mch[(nf * 16 + fr) * 64 + w * 16 + fq * 4]) = o;
  }
}

// ---------------- scan chain: S0_{c+1} = aend_c * (S0_c + Mc_c) ---------------
// reads McT bf16 coalesced, writes S0F in B-frag layout (n=j, k=i). No syncs.
__global__ __launch_bounds__(256) void scan_chain2(
    const ushort* __restrict__ McT, const float* __restrict__ aend,
    ushort* __restrict__ S0F) {
  const int bh = blockIdx.x;
  const int j = threadIdx.x >> 2, i0 = (threadIdx.x & 3) * 16;
  const int fbase = ((j >> 4) * 2 + (i0 >> 5)) * 512 + (((i0 >> 3) & 3) * 16 + (j & 15)) * 8;
  float S[16];
#pragma unroll
  for (int p = 0; p < 16; ++p) S[p] = 0.f;
  for (int c = 0; c < NC; ++c) {
    const ushort* mch = McT + ((size_t)bh * NC + c) * 4096 + j * 64 + i0;
    bf16x8 m0 = *reinterpret_cast<const bf16x8*>(mch);
    bf16x8 m1 = *reinterpret_cast<const bf16x8*>(mch + 8);
    const float* ae = aend + ((size_t)bh * NC + c) * 64 + i0;
    float av[16];
#pragma unroll
    for (int q = 0; q < 4; ++q) {
      float4 aq = *(const float4*)(ae + q * 4);
      av[q * 4 + 0] = aq.x; av[q * 4 + 1] = aq.y; av[q * 4 + 2] = aq.z; av[q * 4 + 3] = aq.w;
    }
    ushort* s0 = S0F + ((size_t)bh * NC + c) * 4096 + fbase;
    ushort4 o0, o1, o2, o3;
    o0.x = f2bf(S[0]); o0.y = f2bf(S[1]); o0.z = f2bf(S[2]); o0.w = f2bf(S[3]);
    o1.x = f2bf(S[4]); o1.y = f2bf(S[5]); o1.z = f2bf(S[6]); o1.w = f2bf(S[7]);
    o2.x = f2bf(S[8]); o2.y = f2bf(S[9]); o2.z = f2bf(S[10]); o2.w = f2bf(S[11]);
    o3.x = f2bf(S[12]); o3.y = f2bf(S[13]); o3.z = f2bf(S[14]); o3.w = f2bf(S[15]);
    *reinterpret_cast<ushort4*>(s0) = o0;
    *reinterpret_cast<ushort4*>(s0 + 4) = o1;
    *reinterpret_cast<ushort4*>(s0 + 128) = o2;
    *reinterpret_cast<ushort4*>(s0 + 132) = o3;
#pragma unroll
    for (int p = 0; p < 8; ++p) S[p] = av[p] * (S[p] + bf2f((ushort)m0[p]));
#pragma unroll
    for (int p = 0; p < 8; ++p) S[8 + p] = av[8 + p] * (S[8 + p] + bf2f((ushort)m1[p]));
  }
}

// ---------------- scan y2: walk + A=causal(kA.kIA^T); y = kA.S0 + A.V; y*r ----
__global__ __launch_bounds__(256) void scan_y2(
    const ushort* __restrict__ kb, const float* __restrict__ df,
    const ushort* __restrict__ vbF, const ushort* __restrict__ rb,
    const ushort* __restrict__ S0F, ushort* __restrict__ yrow) {
  __shared__ float dt[64 * 68];
  __shared__ ushort kt[64 * 72];
  __shared__ ushort kAf[4096];    // A-frag (m=t, k=i), swizzled
  __shared__ ushort kIAf[4096];   // B-frag (n=s, k=i), swizzled
  __shared__ ushort Am[64 * 72];
  __shared__ float part[256];
  const int bh = blockIdx.x, c = blockIdx.y;
  const int b = bh / H_, h = bh % H_;
  const int tid = threadIdx.x;
  const int w = tid >> 6, lane = tid & 63;
  const int fr = lane & 15, fq = lane >> 4;
  {
    const int row = tid >> 2, c16 = (tid & 3) * 16;
    const ushort* gk = kb + ((size_t)(b * T_ + c * TC + row)) * D_ + h * HS_ + c16;
    const float* gd = df + ((size_t)(b * T_ + c * TC + row)) * D_ + h * HS_ + c16;
    uint4 k0 = *(const uint4*)gk;
    uint4 k1 = *(const uint4*)(gk + 8);
    *(uint4*)&kt[row * 72 + c16] = k0;
    *(uint4*)&kt[row * 72 + c16 + 8] = k1;
#pragma unroll
    for (int q = 0; q < 4; ++q)
      *(float4*)&dt[row * 68 + c16 + q * 4] = *(const float4*)(gd + q * 4);
  }
  __syncthreads();
  float p = 1.f;
#pragma unroll
  for (int tt = 0; tt < 16; ++tt) p *= dt[(w * 16 + tt) * 68 + lane];
  part[w * 64 + lane] = p;
  __syncthreads();
  float a = 1.f;
  for (int w2 = 0; w2 < w; ++w2) a *= part[w2 * 64 + lane];
  const int swz = fragswz(lane);
#pragma unroll
  for (int tt = 0; tt < 16; ++tt) {
    int t = w * 16 + tt;
    float d = dt[t * 68 + lane];
    float k = bf2f(kt[t * 72 + lane]);
    a *= d;
    int ad = fragaddr(t, lane) ^ swz;
    kAf[ad] = f2bf(k * a);
    kIAf[ad] = f2bf(k / a);
  }
  __syncthreads();

  // A-frags for rows t in [16w, 16w+16): frag (w, kk), reader XOR
  bf16x8 af[2];
#pragma unroll
  for (int kk = 0; kk < 2; ++kk) {
    int ra = ((w * 2 + kk) * 512 + lane * 8) ^ (((lane >> 4) << 3) ^ (kk << 5));
    af[kk] = *reinterpret_cast<const bf16x8*>(&kAf[ra]);
  }
  // ---- phase A: S[t][s] = sum_i kA[t][i]*kIA[s][i]; causal mask -> Am ----
  {
    f32x4 accA[4];
#pragma unroll
    for (int nf = 0; nf < 4; ++nf) accA[nf] = (f32x4){0.f, 0.f, 0.f, 0.f};
#pragma unroll
    for (int kk = 0; kk < 2; ++kk)
#pragma unroll
      for (int nf = 0; nf < 4; ++nf) {
        int rb8 = ((nf * 2 + kk) * 512 + lane * 8) ^ (((lane >> 4) << 3) ^ (kk << 5));
        bf16x8 b8 = *reinterpret_cast<const bf16x8*>(&kIAf[rb8]);
        accA[nf] = __builtin_amdgcn_mfma_f32_16x16x32_bf16(af[kk], b8, accA[nf], 0, 0, 0);
      }
#pragma unroll
    for (int nf = 0; nf < 4; ++nf)
#pragma unroll
      for (int rr = 0; rr < 4; ++rr) {
        int t = w * 16 + fq * 4 + rr;
        int s = nf * 16 + fr;
        float val = (s <= t) ? accA[nf][rr] : 0.f;
        Am[t * 72 + s] = f2bf(val);
      }
  }
  __syncthreads();

  // ---- phase B: Y = kA*S0 + Am*V ----
  f32x4 accY[4];
#pragma unroll
  for (int nf = 0; nf < 4; ++nf) accY[nf] = (f32x4){0.f, 0.f, 0.f, 0.f};
  const ushort* s0ch = S0F + ((size_t)bh * NC + c) * 4096;
  const ushort* vch = vbF + ((size_t)bh * NC + c) * 4096;
#pragma unroll
  for (int kk = 0; kk < 2; ++kk)
#pragma unroll
    for (int nf = 0; nf < 4; ++nf) {
      bf16x8 b8 = *reinterpret_cast<const bf16x8*>(s0ch + (nf * 2 + kk) * 512 + lane * 8);
      accY[nf] = __builtin_amdgcn_mfma_f32_16x16x32_bf16(af[kk], b8, accY[nf], 0, 0, 0);
    }
#pragma unroll
  for (int kk = 0; kk < 2; ++kk) {
    bf16x8 am8 = *reinterpret_cast<const bf16x8*>(&Am[(w * 16 + fr) * 72 + kk * 32 + fq * 8]);
#pragma unroll
    for (int nf = 0; nf < 4; ++nf) {
      bf16x8 b8 = *reinterpret_cast<const bf16x8*>(vch + (nf * 2 + kk) * 512 + lane * 8);
      accY[nf] = __builtin_amdgcn_mfma_f32_16x16x32_bf16(am8, b8, accY[nf], 0, 0, 0);
    }
  }
#pragma unroll
  for (int nf = 0; nf < 4; ++nf)
#pragma unroll
    for (int rr = 0; rr < 4; ++rr) {
      int t = w * 16 + fq * 4 + rr;
      int j = nf * 16 + fr;
      size_t go = ((size_t)b * T_ + (size_t)c * TC + t) * D_ + h * HS_ + j;
      float rv = bf2f(rb[go]);
      yrow[go] = f2bf(accY[nf][rr] * rv);
    }
}

// ---------------- launch ----------------
extern "C" void kernel_launch(void* const* d_in, const int* in_sizes, int n_in,
                              void* d_out, int out_size, void* d_ws, size_t ws_size,
                              hipStream_t stream) {
  const float* x     = (const float*)d_in[0];
  const float* Wx    = (const float*)d_in[1];
  const float* Ww    = (const float*)d_in[2];
  const float* bw    = (const float*)d_in[3];
  const float* Wk    = (const float*)d_in[4];
  const float* Wv    = (const float*)d_in[5];
  const float* Wr    = (const float*)d_in[6];
  const float* Wo    = (const float*)d_in[7];
  const float* gamma = (const float*)d_in[8];
  const float* beta  = (const float*)d_in[9];
  float* out = (float*)d_out;

  // workspace (bytes), NEED proven round 3-6:
  //   xn  [0,          25165824)  bf16 xn -> McT bf16 (3072 x 8KB, after gemm_cat)
  //   wb  [25165824,   32243712)
  //   xp  [32243712,   57409536)  bf16 xp -> S0F bf16 (3072 x 8KB, after decay gemm)
  //   kb  [57409536,   82575360)
  //   vbF [82575360,  107741184)  v in fragment layout per (bh,c)
  //   rb  [107741184, 132907008)
  //   yr  [132907008, 158072832)  head = aend fp32 (dead before scan_y2 writes)
  //   df  [158072832, 208404480)  fp32 decay (live through scan_y2)
  const size_t NEED = 208404480ull;
  if (ws_size < NEED) {
    zero_out_kernel<<<2048, 256, 0, stream>>>(out, out_size);
    return;
  }

  char* ws = (char*)d_ws;
  ushort* xn = (ushort*)ws;
  ushort* wb = (ushort*)(ws + 25165824);
  ushort* xp = (ushort*)(ws + 32243712);
  ushort* kb = (ushort*)(ws + 57409536);
  ushort* vbF = (ushort*)(ws + 82575360);
  ushort* rb = (ushort*)(ws + 107741184);
  ushort* yr = (ushort*)(ws + 132907008);
  float*  df = (float*)(ws + 158072832);
  ushort* McT = (ushort*)ws;                 // aliases xn (dead after gemm_cat)
  ushort* S0F = (ushort*)(ws + 32243712);    // aliases xp (dead after decay gemm)
  float*  aendb = (float*)(ws + 132907008);  // yr head

  ushort* WcatB = wb;  // rows: [Wk; Wv; Wr; Wx]
  ushort* WwB = wb + 4 * 589824;
  ushort* WoB = wb + 5 * 589824;

  cast_w_kernel<<<576, 256, 0, stream>>>(Wk, WcatB);
  cast_w_kernel<<<576, 256, 0, stream>>>(Wv, WcatB + 589824);
  cast_w_kernel<<<576, 256, 0, stream>>>(Wr, WcatB + 2 * 589824);
  cast_w_kernel<<<576, 256, 0, stream>>>(Wx, WcatB + 3 * 589824);
  cast_w_kernel<<<576, 256, 0, stream>>>(Ww, WwB);
  cast_w_kernel<<<576, 256, 0, stream>>>(Wo, WoB);
  ln_kernel<<<4096, 256, 0, stream>>>(x, gamma, beta, xn);

  gemm256<<<dim3(64, 12), 512, 0, stream>>>(xn, WcatB, nullptr, kb, vbF, rb, xp,
                                            nullptr, 5);
  gemm256<<<dim3(64, 3), 512, 0, stream>>>(xp, WwB, df, nullptr, nullptr, nullptr,
                                           nullptr, bw, 3);

  scan_mc2<<<dim3(96, NC), 256, 0, stream>>>(kb, df, vbF, McT, aendb);
  scan_chain2<<<96, 256, 0, stream>>>(McT, aendb, S0F);
  scan_y2<<<dim3(96, NC), 256, 0, stream>>>(kb, df, vbF, rb, S0F, yr);

  gemm256<<<dim3(64, 3), 512, 0, stream>>>(yr, WoB, out, nullptr, nullptr, nullptr,
                                           nullptr, nullptr, 0);
}

// Round 8
// 251.101 us; speedup vs baseline: 1.7230x; 1.7230x over previous
//
#include <hip/hip_runtime.h>

#define B_ 8
#define T_ 2048
#define D_ 768
#define H_ 12
#define HS_ 64
#define LN_EPS 1e-5f
#define NC 32   // chunks
#define TC 64   // timesteps per chunk

typedef __attribute__((ext_vector_type(8))) short bf16x8;
typedef __attribute__((ext_vector_type(4))) float f32x4;

__device__ __forceinline__ ushort f2bf(float f) {
  unsigned u = __builtin_bit_cast(unsigned, f);
  unsigned r = (u + 0x7FFFu + ((u >> 16) & 1u)) >> 16;
  return (ushort)r;
}
__device__ __forceinline__ float bf2f(ushort u) {
  return __builtin_bit_cast(float, ((unsigned)u) << 16);
}

// fragment address: element (row t, col i) of a 64x64 tile in MFMA A/B-frag
// layout (m/n = t, k = i). 8 frags x 512 halves.
__device__ __forceinline__ int fragaddr(int t, int i) {
  return ((t >> 4) * 2 + (i >> 5)) * 512 + ((((i >> 3) & 3) * 16) + (t & 15)) * 8 + (i & 7);
}
__device__ __forceinline__ int fragswz(int i) {
  return (((i >> 3) & 3) << 3) ^ (((i >> 5) & 1) << 5);
}

// ---------------- canary ----------------
__global__ __launch_bounds__(256) void zero_out_kernel(float* __restrict__ out, int n) {
  for (int i = blockIdx.x * 256 + threadIdx.x; i < n; i += gridDim.x * 256)
    out[i] = 0.f;
}

// ---------------- weight cast: 5 sources -> slots {0,1,2,4,5} ----------------
__global__ __launch_bounds__(256) void cast5_kernel(
    const float* __restrict__ w0, const float* __restrict__ w1,
    const float* __restrict__ w2, const float* __restrict__ w3,
    const float* __restrict__ w4, ushort* __restrict__ dst) {
  const float* srcs[5] = {w0, w1, w2, w3, w4};
  const int slots[5] = {0, 1, 2, 4, 5};
  const float* src = srcs[blockIdx.y];
  ushort* d = dst + (size_t)slots[blockIdx.y] * 589824;
  int idx = (blockIdx.x * 256 + threadIdx.x) * 4;
  float4 v = *reinterpret_cast<const float4*>(src + idx);
  ushort4 o;
  o.x = f2bf(v.x); o.y = f2bf(v.y); o.z = f2bf(v.z); o.w = f2bf(v.w);
  *reinterpret_cast<ushort4*>(d + idx) = o;
}

// ---------------- transpose-cast: WxT[d][e] = Wx[e][d] (fp32 -> bf16) --------
__global__ __launch_bounds__(256) void transpose_cast_kernel(
    const float* __restrict__ src, ushort* __restrict__ dst) {
  __shared__ ushort tile[32][33];
  const int bx = blockIdx.x * 32;  // src col (d)
  const int by = blockIdx.y * 32;  // src row (e)
  const int tx = threadIdx.x & 31, ty = threadIdx.x >> 5;
#pragma unroll
  for (int r = 0; r < 32; r += 8)
    tile[ty + r][tx] = f2bf(src[(size_t)(by + ty + r) * 768 + bx + tx]);
  __syncthreads();
#pragma unroll
  for (int r = 0; r < 32; r += 8)
    dst[(size_t)(bx + ty + r) * 768 + by + tx] = tile[tx][ty + r];
}

// ---------------- LayerNorm ----------------
__global__ __launch_bounds__(256) void ln_kernel(
    const float* __restrict__ x, const float* __restrict__ gamma,
    const float* __restrict__ beta, ushort* __restrict__ xn) {
  const int wv = threadIdx.x >> 6;
  const int lane = threadIdx.x & 63;
  const int row = blockIdx.x * 4 + wv;
  const float* xr = x + (size_t)row * D_;
  float4 a[3];
#pragma unroll
  for (int s = 0; s < 3; ++s)
    a[s] = *reinterpret_cast<const float4*>(xr + s * 256 + lane * 4);
  float sum = 0.f;
#pragma unroll
  for (int s = 0; s < 3; ++s) sum += a[s].x + a[s].y + a[s].z + a[s].w;
#pragma unroll
  for (int off = 32; off; off >>= 1) sum += __shfl_xor(sum, off);
  float mu = sum * (1.f / 768.f);
  float vs = 0.f;
#pragma unroll
  for (int s = 0; s < 3; ++s) {
    float dx = a[s].x - mu, dy = a[s].y - mu, dz = a[s].z - mu, dw = a[s].w - mu;
    vs += dx * dx + dy * dy + dz * dz + dw * dw;
  }
#pragma unroll
  for (int off = 32; off; off >>= 1) vs += __shfl_xor(vs, off);
  float rs = rsqrtf(vs * (1.f / 768.f) + LN_EPS);
  ushort* orow = xn + (size_t)row * D_;
#pragma unroll
  for (int s = 0; s < 3; ++s) {
    int col = s * 256 + lane * 4;
    float4 g = *reinterpret_cast<const float4*>(gamma + col);
    float4 bb = *reinterpret_cast<const float4*>(beta + col);
    ushort4 o;
    o.x = f2bf((a[s].x - mu) * rs * g.x + bb.x);
    o.y = f2bf((a[s].y - mu) * rs * g.y + bb.y);
    o.z = f2bf((a[s].z - mu) * rs * g.z + bb.z);
    o.w = f2bf((a[s].w - mu) * rs * g.w + bb.w);
    *reinterpret_cast<ushort4*>(orow + col) = o;
  }
}

// ---------------- 256x256 8-phase bf16 MFMA GEMM (r6-proven schedule) --------
// C[m,n] = sum_k A[m,k]*W[n,k].  K=768. 512 threads = 8 waves (2M x 4N).
// modes: 0 fp32 plain
//        5 cat -> sel0: k bf16 | sel1: v FRAG layout | sel2: r sigmoid bf16
//                 sel3: decay fp32 = 1-sigmoid(val+bias) -> Cf
__global__ __launch_bounds__(512, 2) void gemm256(
    const ushort* __restrict__ A, const ushort* __restrict__ W,
    float* __restrict__ Cf,
    ushort* __restrict__ d0, ushort* __restrict__ d1, ushort* __restrict__ d2,
    const float* __restrict__ bias, int mode) {
  __shared__ __align__(16) ushort lds[65536];  // 128 KiB
  const int tid = threadIdx.x;
  const int wid = tid >> 6;
  const int lane = tid & 63;
  const int wr = wid >> 2, wc = wid & 3;
  const int fr = lane & 15, fq = lane >> 4;
  const int m0 = blockIdx.x * 256, n0 = blockIdx.y * 256;
  const int strow = tid >> 3;
  const int stblk = tid & 7;

  const int RA0 = wr * 8192;
  const int RA1 = 32768 + wr * 8192;
  const int RB0 = 16384 + (wc >> 1) * 8192 + (wc & 1) * 4096;
  const int RB1 = 49152 + (wc >> 1) * 8192 + (wc & 1) * 4096;

  f32x4 acc[8][4];
#pragma unroll
  for (int m = 0; m < 8; ++m)
#pragma unroll
    for (int n = 0; n < 4; ++n) acc[m][n] = (f32x4){0.f, 0.f, 0.f, 0.f};

#define STAGE_HALF(gb, grow0, kk0, roff)                                          \
  {                                                                               \
    _Pragma("unroll") for (int j = 0; j < 2; ++j) {                               \
      const int lr_ = j * 64 + strow;                                             \
      const int bs_ = stblk ^ (lr_ & 7);                                          \
      const ushort* s_ = (gb) + (size_t)((grow0) + lr_) * 768 + (kk0) + bs_ * 8;  \
      __builtin_amdgcn_global_load_lds(                                           \
          (const __attribute__((address_space(1))) void*)s_,                      \
          (__attribute__((address_space(3))) void*)(lds + (roff) + j * 4096 + wid * 512), \
          16, 0, 0);                                                              \
    }                                                                             \
  }

#define LDF(dst, base, rf, kk)                                                    \
  dst = *reinterpret_cast<const bf16x8*>(                                         \
      lds + (base) + ((rf)*16 + fr) * 64 + ((((kk)*4 + fq) ^ (fr & 7)) * 8));

#define MFMA_Q(mb, nb, aa, bb)                                                    \
  __builtin_amdgcn_s_setprio(1);                                                  \
  _Pragma("unroll") for (int m_ = 0; m_ < 4; ++m_)                                \
  _Pragma("unroll") for (int n_ = 0; n_ < 2; ++n_)                                \
  _Pragma("unroll") for (int k_ = 0; k_ < 2; ++k_)                                \
    acc[(mb) + m_][(nb) + n_] = __builtin_amdgcn_mfma_f32_16x16x32_bf16(          \
        aa[m_][k_], bb[n_][k_], acc[(mb) + m_][(nb) + n_], 0, 0, 0);              \
  __builtin_amdgcn_s_setprio(0);

  // ---- prologue: A0, B0 -> buf0; B1 -> buf1 ----
  STAGE_HALF(A, m0, 0, 0);
  STAGE_HALF(A, m0 + 128, 0, 8192);
  STAGE_HALF(W, n0, 0, 16384);
  STAGE_HALF(W, n0 + 128, 0, 24576);
  STAGE_HALF(W, n0, 64, 49152);
  STAGE_HALF(W, n0 + 128, 64, 57344);
  asm volatile("s_waitcnt vmcnt(4)" ::: "memory");
  __builtin_amdgcn_s_barrier();

  bf16x8 aL[4][2], aH[4][2], bL[2][2], bH[2][2];

  for (int i = 0; i < 6; ++i) {
    const int kQ = (2 * i + 1) * 64;
    const int kP2 = (2 * i + 2 <= 11 ? 2 * i + 2 : 11) * 64;
    const int kQ2 = (2 * i + 3 <= 11 ? 2 * i + 3 : 11) * 64;

    // ======== tile P = 2i (buf0) ========
    STAGE_HALF(A, m0, kQ, 32768);
#pragma unroll
    for (int m = 0; m < 4; ++m) { LDF(aL[m][0], RA0, m, 0); LDF(aL[m][1], RA0, m, 1); }
#pragma unroll
    for (int n = 0; n < 2; ++n) { LDF(bL[n][0], RB0, n, 0); LDF(bL[n][1], RB0, n, 1); }
    __builtin_amdgcn_s_barrier();
    MFMA_Q(0, 0, aL, bL);
    __builtin_amdgcn_s_barrier();

    STAGE_HALF(A, m0 + 128, kQ, 40960);
#pragma unroll
    for (int n = 0; n < 2; ++n) { LDF(bH[n][0], RB0, n + 2, 0); LDF(bH[n][1], RB0, n + 2, 1); }
    __builtin_amdgcn_s_barrier();
    MFMA_Q(0, 2, aL, bH);
    __builtin_amdgcn_s_barrier();

    STAGE_HALF(W, n0, kP2, 16384);
#pragma unroll
    for (int m = 0; m < 4; ++m) { LDF(aH[m][0], RA0, m + 4, 0); LDF(aH[m][1], RA0, m + 4, 1); }
    __builtin_amdgcn_s_barrier();
    MFMA_Q(4, 0, aH, bL);
    __builtin_amdgcn_s_barrier();

    STAGE_HALF(W, n0 + 128, kP2, 24576);
    __builtin_amdgcn_s_barrier();
    MFMA_Q(4, 2, aH, bH);
    asm volatile("s_waitcnt vmcnt(4)" ::: "memory");
    __builtin_amdgcn_s_barrier();

    // ======== tile Q = 2i+1 (buf1) ========
    STAGE_HALF(A, m0, kP2, 0);
#pragma unroll
    for (int m = 0; m < 4; ++m) { LDF(aL[m][0], RA1, m, 0); LDF(aL[m][1], RA1, m, 1); }
#pragma unroll
    for (int n = 0; n < 2; ++n) { LDF(bL[n][0], RB1, n, 0); LDF(bL[n][1], RB1, n, 1); }
    __builtin_amdgcn_s_barrier();
    MFMA_Q(0, 0, aL, bL);
    __builtin_amdgcn_s_barrier();

    STAGE_HALF(A, m0 + 128, kP2, 8192);
#pragma unroll
    for (int n = 0; n < 2; ++n) { LDF(bH[n][0], RB1, n + 2, 0); LDF(bH[n][1], RB1, n + 2, 1); }
    __builtin_amdgcn_s_barrier();
    MFMA_Q(0, 2, aL, bH);
    __builtin_amdgcn_s_barrier();

    STAGE_HALF(W, n0, kQ2, 49152);
#pragma unroll
    for (int m = 0; m < 4; ++m) { LDF(aH[m][0], RA1, m + 4, 0); LDF(aH[m][1], RA1, m + 4, 1); }
    __builtin_amdgcn_s_barrier();
    MFMA_Q(4, 0, aH, bL);
    __builtin_amdgcn_s_barrier();

    STAGE_HALF(W, n0 + 128, kQ2, 57344);
    __builtin_amdgcn_s_barrier();
    MFMA_Q(4, 2, aH, bH);
    asm volatile("s_waitcnt vmcnt(4)" ::: "memory");
    __builtin_amdgcn_s_barrier();
  }

  // ---- epilogue ----
  const int r0 = fq * 4;
  if (mode == 5) {
    const int sel = n0 >= 2304 ? 3 : n0 >= 1536 ? 2 : n0 >= 768 ? 1 : 0;
    const int nb = n0 - sel * 768;
    if (sel == 1) {
      // v -> fragment layout per (b,h,chunk) tile
#pragma unroll
      for (int mf = 0; mf < 8; ++mf)
#pragma unroll
        for (int nf = 0; nf < 4; ++nf) {
          int gr = m0 + wr * 128 + mf * 16 + r0;
          int gc = nb + wc * 64 + nf * 16 + fr;
          int b = gr >> 11, t = gr & 2047;
          int c = t >> 6, s0 = t & 63;
          int h = gc >> 6, j = gc & 63;
          size_t addr = ((size_t)((b * 12 + h) * 32 + c)) * 4096 +
                        (size_t)(((j >> 4) * 2 + (s0 >> 5)) * 512 +
                                 (((s0 >> 3) & 3) * 16 + (j & 15)) * 8 + (s0 & 7));
          ushort4 o;
          o.x = f2bf(acc[mf][nf][0]); o.y = f2bf(acc[mf][nf][1]);
          o.z = f2bf(acc[mf][nf][2]); o.w = f2bf(acc[mf][nf][3]);
          *reinterpret_cast<ushort4*>(d1 + addr) = o;
        }
    } else if (sel == 3) {
      // decay fp32 = 1 - sigmoid(val + bias)
#pragma unroll
      for (int mf = 0; mf < 8; ++mf)
#pragma unroll
        for (int nf = 0; nf < 4; ++nf) {
          int gr = m0 + wr * 128 + mf * 16 + r0;
          int gc = nb + wc * 64 + nf * 16 + fr;
          float bv = bias[gc];
#pragma unroll
          for (int rr = 0; rr < 4; ++rr) {
            float u = acc[mf][nf][rr] + bv;
            Cf[(size_t)(gr + rr) * 768 + gc] = 1.f / (1.f + __expf(u));
          }
        }
    } else {
      ushort* dst = sel == 0 ? d0 : d2;
      const bool sig = (sel == 2);
#pragma unroll
      for (int mf = 0; mf < 8; ++mf)
#pragma unroll
        for (int nf = 0; nf < 4; ++nf) {
          int gr = m0 + wr * 128 + mf * 16 + r0;
          int gc = nb + wc * 64 + nf * 16 + fr;
#pragma unroll
          for (int rr = 0; rr < 4; ++rr) {
            float v = acc[mf][nf][rr];
            if (sig) v = 1.f / (1.f + __expf(-v));
            dst[(size_t)(gr + rr) * 768 + gc] = f2bf(v);
          }
        }
    }
  } else {
#pragma unroll
    for (int mf = 0; mf < 8; ++mf)
#pragma unroll
      for (int nf = 0; nf < 4; ++nf) {
        int gr = m0 + wr * 128 + mf * 16 + r0;
        int gc = n0 + wc * 64 + nf * 16 + fr;
#pragma unroll
        for (int rr = 0; rr < 4; ++rr)
          Cf[(size_t)(gr + rr) * 768 + gc] = acc[mf][nf][rr];
      }
  }
#undef STAGE_HALF
#undef LDF
#undef MFMA_Q
}

// ---------------- scan mc2: per (bh,c): walk cumprod + McT = kIA^T V ----------
__global__ __launch_bounds__(256) void scan_mc2(
    const ushort* __restrict__ kb, const float* __restrict__ df,
    const ushort* __restrict__ vbF, ushort* __restrict__ McT,
    float* __restrict__ aend) {
  __shared__ float dt[64 * 68];
  __shared__ ushort kt[64 * 72];
  __shared__ ushort kIAf[4096];
  __shared__ float part[256];
  const int bh = blockIdx.x, c = blockIdx.y;
  const int b = bh / H_, h = bh % H_;
  const int tid = threadIdx.x;
  const int w = tid >> 6, lane = tid & 63;
  {
    const int row = tid >> 2, c16 = (tid & 3) * 16;
    const ushort* gk = kb + ((size_t)(b * T_ + c * TC + row)) * D_ + h * HS_ + c16;
    const float* gd = df + ((size_t)(b * T_ + c * TC + row)) * D_ + h * HS_ + c16;
    uint4 k0 = *(const uint4*)gk;
    uint4 k1 = *(const uint4*)(gk + 8);
    *(uint4*)&kt[row * 72 + c16] = k0;
    *(uint4*)&kt[row * 72 + c16 + 8] = k1;
#pragma unroll
    for (int q = 0; q < 4; ++q)
      *(float4*)&dt[row * 68 + c16 + q * 4] = *(const float4*)(gd + q * 4);
  }
  __syncthreads();
  float p = 1.f;
#pragma unroll
  for (int tt = 0; tt < 16; ++tt) p *= dt[(w * 16 + tt) * 68 + lane];
  part[w * 64 + lane] = p;
  __syncthreads();
  float a = 1.f;
  for (int w2 = 0; w2 < w; ++w2) a *= part[w2 * 64 + lane];
#pragma unroll
  for (int tt = 0; tt < 16; ++tt) {
    int t = w * 16 + tt;
    float d = dt[t * 68 + lane];
    float k = bf2f(kt[t * 72 + lane]);
    a *= d;
    kIAf[fragaddr(lane, t)] = f2bf(k / a);  // A-frag (m=i, k=s)
  }
  if (w == 3) aend[((size_t)bh * NC + c) * 64 + lane] = a;
  __syncthreads();

  const int fr = lane & 15, fq = lane >> 4;
  f32x4 acc[4];
#pragma unroll
  for (int nf = 0; nf < 4; ++nf) acc[nf] = (f32x4){0.f, 0.f, 0.f, 0.f};
  bf16x8 af[2];
  af[0] = *reinterpret_cast<const bf16x8*>(&kIAf[(w * 2 + 0) * 512 + lane * 8]);
  af[1] = *reinterpret_cast<const bf16x8*>(&kIAf[(w * 2 + 1) * 512 + lane * 8]);
  const ushort* vch = vbF + ((size_t)bh * NC + c) * 4096;
#pragma unroll
  for (int kk = 0; kk < 2; ++kk)
#pragma unroll
    for (int nf = 0; nf < 4; ++nf) {
      bf16x8 b8 = *reinterpret_cast<const bf16x8*>(vch + (nf * 2 + kk) * 512 + lane * 8);
      acc[nf] = __builtin_amdgcn_mfma_f32_16x16x32_bf16(af[kk], b8, acc[nf], 0, 0, 0);
    }
  ushort* mch = McT + ((size_t)bh * NC + c) * 4096;
#pragma unroll
  for (int nf = 0; nf < 4; ++nf) {
    ushort4 o;
    o.x = f2bf(acc[nf][0]); o.y = f2bf(acc[nf][1]);
    o.z = f2bf(acc[nf][2]); o.w = f2bf(acc[nf][3]);
    *reinterpret_cast<ushort4*>(&mch[(nf * 16 + fr) * 64 + w * 16 + fq * 4]) = o;
  }
}

// ---------------- scan chain: S0_{c+1} = aend_c * (S0_c + Mc_c) ---------------
__global__ __launch_bounds__(256) void scan_chain2(
    const ushort* __restrict__ McT, const float* __restrict__ aend,
    ushort* __restrict__ S0F) {
  const int bh = blockIdx.x;
  const int j = threadIdx.x >> 2, i0 = (threadIdx.x & 3) * 16;
  const int fbase = ((j >> 4) * 2 + (i0 >> 5)) * 512 + (((i0 >> 3) & 3) * 16 + (j & 15)) * 8;
  float S[16];
#pragma unroll
  for (int p = 0; p < 16; ++p) S[p] = 0.f;
  for (int c = 0; c < NC; ++c) {
    const ushort* mch = McT + ((size_t)bh * NC + c) * 4096 + j * 64 + i0;
    bf16x8 m0 = *reinterpret_cast<const bf16x8*>(mch);
    bf16x8 m1 = *reinterpret_cast<const bf16x8*>(mch + 8);
    const float* ae = aend + ((size_t)bh * NC + c) * 64 + i0;
    float av[16];
#pragma unroll
    for (int q = 0; q < 4; ++q) {
      float4 aq = *(const float4*)(ae + q * 4);
      av[q * 4 + 0] = aq.x; av[q * 4 + 1] = aq.y; av[q * 4 + 2] = aq.z; av[q * 4 + 3] = aq.w;
    }
    ushort* s0 = S0F + ((size_t)bh * NC + c) * 4096 + fbase;
    ushort4 o0, o1, o2, o3;
    o0.x = f2bf(S[0]); o0.y = f2bf(S[1]); o0.z = f2bf(S[2]); o0.w = f2bf(S[3]);
    o1.x = f2bf(S[4]); o1.y = f2bf(S[5]); o1.z = f2bf(S[6]); o1.w = f2bf(S[7]);
    o2.x = f2bf(S[8]); o2.y = f2bf(S[9]); o2.z = f2bf(S[10]); o2.w = f2bf(S[11]);
    o3.x = f2bf(S[12]); o3.y = f2bf(S[13]); o3.z = f2bf(S[14]); o3.w = f2bf(S[15]);
    *reinterpret_cast<ushort4*>(s0) = o0;
    *reinterpret_cast<ushort4*>(s0 + 4) = o1;
    *reinterpret_cast<ushort4*>(s0 + 128) = o2;
    *reinterpret_cast<ushort4*>(s0 + 132) = o3;
#pragma unroll
    for (int p = 0; p < 8; ++p) S[p] = av[p] * (S[p] + bf2f((ushort)m0[p]));
#pragma unroll
    for (int p = 0; p < 8; ++p) S[8 + p] = av[8 + p] * (S[8 + p] + bf2f((ushort)m1[p]));
  }
}

// ---------------- scan y2: walk + A=causal(kA.kIA^T); y = kA.S0 + A.V; y*r ----
__global__ __launch_bounds__(256) void scan_y2(
    const ushort* __restrict__ kb, const float* __restrict__ df,
    const ushort* __restrict__ vbF, const ushort* __restrict__ rb,
    const ushort* __restrict__ S0F, ushort* __restrict__ yrow) {
  __shared__ float dt[64 * 68];
  __shared__ ushort kt[64 * 72];
  __shared__ ushort kAf[4096];
  __shared__ ushort kIAf[4096];
  __shared__ ushort Am[64 * 72];
  __shared__ float part[256];
  const int bh = blockIdx.x, c = blockIdx.y;
  const int b = bh / H_, h = bh % H_;
  const int tid = threadIdx.x;
  const int w = tid >> 6, lane = tid & 63;
  const int fr = lane & 15, fq = lane >> 4;
  {
    const int row = tid >> 2, c16 = (tid & 3) * 16;
    const ushort* gk = kb + ((size_t)(b * T_ + c * TC + row)) * D_ + h * HS_ + c16;
    const float* gd = df + ((size_t)(b * T_ + c * TC + row)) * D_ + h * HS_ + c16;
    uint4 k0 = *(const uint4*)gk;
    uint4 k1 = *(const uint4*)(gk + 8);
    *(uint4*)&kt[row * 72 + c16] = k0;
    *(uint4*)&kt[row * 72 + c16 + 8] = k1;
#pragma unroll
    for (int q = 0; q < 4; ++q)
      *(float4*)&dt[row * 68 + c16 + q * 4] = *(const float4*)(gd + q * 4);
  }
  __syncthreads();
  float p = 1.f;
#pragma unroll
  for (int tt = 0; tt < 16; ++tt) p *= dt[(w * 16 + tt) * 68 + lane];
  part[w * 64 + lane] = p;
  __syncthreads();
  float a = 1.f;
  for (int w2 = 0; w2 < w; ++w2) a *= part[w2 * 64 + lane];
  const int swz = fragswz(lane);
#pragma unroll
  for (int tt = 0; tt < 16; ++tt) {
    int t = w * 16 + tt;
    float d = dt[t * 68 + lane];
    float k = bf2f(kt[t * 72 + lane]);
    a *= d;
    int ad = fragaddr(t, lane) ^ swz;
    kAf[ad] = f2bf(k * a);
    kIAf[ad] = f2bf(k / a);
  }
  __syncthreads();

  bf16x8 af[2];
#pragma unroll
  for (int kk = 0; kk < 2; ++kk) {
    int ra = ((w * 2 + kk) * 512 + lane * 8) ^ (((lane >> 4) << 3) ^ (kk << 5));
    af[kk] = *reinterpret_cast<const bf16x8*>(&kAf[ra]);
  }
  {
    f32x4 accA[4];
#pragma unroll
    for (int nf = 0; nf < 4; ++nf) accA[nf] = (f32x4){0.f, 0.f, 0.f, 0.f};
#pragma unroll
    for (int kk = 0; kk < 2; ++kk)
#pragma unroll
      for (int nf = 0; nf < 4; ++nf) {
        int rb8 = ((nf * 2 + kk) * 512 + lane * 8) ^ (((lane >> 4) << 3) ^ (kk << 5));
        bf16x8 b8 = *reinterpret_cast<const bf16x8*>(&kIAf[rb8]);
        accA[nf] = __builtin_amdgcn_mfma_f32_16x16x32_bf16(af[kk], b8, accA[nf], 0, 0, 0);
      }
#pragma unroll
    for (int nf = 0; nf < 4; ++nf)
#pragma unroll
      for (int rr = 0; rr < 4; ++rr) {
        int t = w * 16 + fq * 4 + rr;
        int s = nf * 16 + fr;
        float val = (s <= t) ? accA[nf][rr] : 0.f;
        Am[t * 72 + s] = f2bf(val);
      }
  }
  __syncthreads();

  f32x4 accY[4];
#pragma unroll
  for (int nf = 0; nf < 4; ++nf) accY[nf] = (f32x4){0.f, 0.f, 0.f, 0.f};
  const ushort* s0ch = S0F + ((size_t)bh * NC + c) * 4096;
  const ushort* vch = vbF + ((size_t)bh * NC + c) * 4096;
#pragma unroll
  for (int kk = 0; kk < 2; ++kk)
#pragma unroll
    for (int nf = 0; nf < 4; ++nf) {
      bf16x8 b8 = *reinterpret_cast<const bf16x8*>(s0ch + (nf * 2 + kk) * 512 + lane * 8);
      accY[nf] = __builtin_amdgcn_mfma_f32_16x16x32_bf16(af[kk], b8, accY[nf], 0, 0, 0);
    }
#pragma unroll
  for (int kk = 0; kk < 2; ++kk) {
    bf16x8 am8 = *reinterpret_cast<const bf16x8*>(&Am[(w * 16 + fr) * 72 + kk * 32 + fq * 8]);
#pragma unroll
    for (int nf = 0; nf < 4; ++nf) {
      bf16x8 b8 = *reinterpret_cast<const bf16x8*>(vch + (nf * 2 + kk) * 512 + lane * 8);
      accY[nf] = __builtin_amdgcn_mfma_f32_16x16x32_bf16(am8, b8, accY[nf], 0, 0, 0);
    }
  }
#pragma unroll
  for (int nf = 0; nf < 4; ++nf)
#pragma unroll
    for (int rr = 0; rr < 4; ++rr) {
      int t = w * 16 + fq * 4 + rr;
      int j = nf * 16 + fr;
      size_t go = ((size_t)b * T_ + (size_t)c * TC + t) * D_ + h * HS_ + j;
      float rv = bf2f(rb[go]);
      yrow[go] = f2bf(accY[nf][rr] * rv);
    }
}

// ---------------- launch ----------------
extern "C" void kernel_launch(void* const* d_in, const int* in_sizes, int n_in,
                              void* d_out, int out_size, void* d_ws, size_t ws_size,
                              hipStream_t stream) {
  const float* x     = (const float*)d_in[0];
  const float* Wx    = (const float*)d_in[1];
  const float* Ww    = (const float*)d_in[2];
  const float* bw    = (const float*)d_in[3];
  const float* Wk    = (const float*)d_in[4];
  const float* Wv    = (const float*)d_in[5];
  const float* Wr    = (const float*)d_in[6];
  const float* Wo    = (const float*)d_in[7];
  const float* gamma = (const float*)d_in[8];
  const float* beta  = (const float*)d_in[9];
  float* out = (float*)d_out;

  // workspace (bytes), NEED proven rounds 3-7:
  //   xn   [0,          25165824)  bf16 xn -> McT (after cat)
  //   wb   [25165824,   32243712)  6 slots: Wk,Wv,Wr,M,Wo,Ww
  //   xp   [32243712,   57409536)  head: WxT (dead after M-gemm) -> S0F
  //   kb   [57409536,   82575360)
  //   vbF  [82575360,  107741184)  v fragment layout
  //   rb   [107741184, 132907008)
  //   yr   [132907008, 158072832)  head = aend fp32 (dead before scan_y2 writes)
  //   df   [158072832, 208404480)  fp32 decay
  const size_t NEED = 208404480ull;
  if (ws_size < NEED) {
    zero_out_kernel<<<2048, 256, 0, stream>>>(out, out_size);
    return;
  }

  char* ws = (char*)d_ws;
  ushort* xn  = (ushort*)ws;
  ushort* wb  = (ushort*)(ws + 25165824);
  ushort* WxT = (ushort*)(ws + 32243712);
  ushort* kb  = (ushort*)(ws + 57409536);
  ushort* vbF = (ushort*)(ws + 82575360);
  ushort* rb  = (ushort*)(ws + 107741184);
  ushort* yr  = (ushort*)(ws + 132907008);
  float*  df  = (float*)(ws + 158072832);
  ushort* McT = (ushort*)ws;                 // aliases xn
  ushort* S0F = (ushort*)(ws + 32243712);    // aliases WxT region (dead by then)
  float*  aendb = (float*)(ws + 132907008);  // yr head

  ushort* WcatB = wb;                 // slots 0..3: Wk, Wv, Wr, M
  ushort* Mb  = wb + 3 * 589824;
  ushort* WoB = wb + 4 * 589824;
  ushort* WwB = wb + 5 * 589824;

  cast5_kernel<<<dim3(576, 5), 256, 0, stream>>>(Wk, Wv, Wr, Wo, Ww, wb);
  transpose_cast_kernel<<<dim3(24, 24), 256, 0, stream>>>(Wx, WxT);
  // composite M = Ww @ Wx  (M[f][d] = sum_e Ww[f][e] * Wx[e][d])
  gemm256<<<dim3(3, 3), 512, 0, stream>>>(WwB, WxT, nullptr, Mb, nullptr, nullptr,
                                          nullptr, 5);
  ln_kernel<<<4096, 256, 0, stream>>>(x, gamma, beta, xn);

  // fused k/v/r/decay GEMM (N=3072): k bf16, v frag, r sigmoid, decay fp32+bias
  gemm256<<<dim3(64, 12), 512, 0, stream>>>(xn, WcatB, df, kb, vbF, rb, bw, 5);

  scan_mc2<<<dim3(96, NC), 256, 0, stream>>>(kb, df, vbF, McT, aendb);
  scan_chain2<<<96, 256, 0, stream>>>(McT, aendb, S0F);
  scan_y2<<<dim3(96, NC), 256, 0, stream>>>(kb, df, vbF, rb, S0F, yr);

  // final GEMM (N=768): fp32 out
  gemm256<<<dim3(64, 3), 512, 0, stream>>>(yr, WoB, out, nullptr, nullptr, nullptr,
                                           nullptr, 0);
}